// Round 5
// baseline (337.133 us; speedup 1.0000x reference)
//
#include <hip/hip_runtime.h>

typedef short short8 __attribute__((ext_vector_type(8)));
typedef float f32x4 __attribute__((ext_vector_type(4)));

// ---------------- bf16 helpers ----------------

__device__ inline unsigned short f2bf(float f) {
    union { float f; unsigned u; } v; v.f = f;
    unsigned r = v.u + 0x7fffu + ((v.u >> 16) & 1u);
    return (unsigned short)(r >> 16);
}
__device__ inline unsigned pack2(float a, float b) {
    return (unsigned)f2bf(a) | ((unsigned)f2bf(b) << 16);
}
__device__ inline float bflo(unsigned u) { union { unsigned q; float f; } c; c.q = u << 16; return c.f; }
__device__ inline float bfhi(unsigned u) { union { unsigned q; float f; } c; c.q = u & 0xffff0000u; return c.f; }

#define ACC8(vv)                                     \
    acc[0] += bflo(vv.x); acc[1] += bfhi(vv.x);      \
    acc[2] += bflo(vv.y); acc[3] += bfhi(vv.y);      \
    acc[4] += bflo(vv.z); acc[5] += bfhi(vv.z);      \
    acc[6] += bflo(vv.w); acc[7] += bfhi(vv.w);

// ---------------- CSR build: atomic-free two-level bucket sort ----------------

#define EPB 2048
#define NE 8
#define BSH 9
#define MAXBKT 128
#define DCAP 10240

// mega1: binA (blocks [0,nblk)) + feature->bf16 cvt + weight transposes, one launch
__global__ __launch_bounds__(256) void mega1(const int* __restrict__ dst, int* __restrict__ cnt2d,
                                             int e, int nbkt, int nblk,
                                             const float4* __restrict__ feat, uint2* __restrict__ featb,
                                             int cvtb, int nf4,
                                             const float* __restrict__ W1, const float* __restrict__ Wh,
                                             const float* __restrict__ Wo,
                                             unsigned short* __restrict__ W1t, unsigned short* __restrict__ Wht,
                                             unsigned short* __restrict__ Wot) {
    __shared__ int hist[MAXBKT];
    int t = threadIdx.x, b = blockIdx.x;
    if (b < nblk) {
        for (int j = t; j < nbkt; j += 256) hist[j] = 0;
        __syncthreads();
        int base = b * EPB;
#pragma unroll
        for (int j = 0; j < NE; j++) {
            int idx = base + t + 256 * j;
            if (idx < e) atomicAdd(&hist[dst[idx] >> BSH], 1);
        }
        __syncthreads();
        for (int j = t; j < nbkt; j += 256) cnt2d[j * nblk + b] = hist[j];
    } else if (b < nblk + cvtb) {
        int i = (b - nblk) * 256 + t;
        if (i < nf4) {
            float4 v = feat[i];
            featb[i] = make_uint2(pack2(v.x, v.y), pack2(v.z, v.w));
        }
    } else {
        int i = (b - nblk - cvtb) * 256 + t;
        if (i < 16384) {
            int k = i >> 7, nn = i & 127;
            W1t[nn * 128 + k] = f2bf(W1[i]);
        } else if (i < 32768) {
            int j = i - 16384, k = j >> 7, nn = j & 127;
            Wht[nn * 128 + k] = f2bf(Wh[j]);
        } else if (i < 40960) {
            int j = i - 32768, k = j >> 6, nn = j & 63;
            Wot[nn * 128 + k] = f2bf(Wo[j]);
        }
    }
}

__global__ __launch_bounds__(512) void scanB1(int* __restrict__ cnt2d, int* __restrict__ totals, int nblk) {
    __shared__ int s[512];
    int t = threadIdx.x, b = blockIdx.x;
    int v = (t < nblk) ? cnt2d[b * nblk + t] : 0;
    s[t] = v;
    __syncthreads();
    for (int off = 1; off < 512; off <<= 1) {
        int u = (t >= off) ? s[t - off] : 0;
        __syncthreads();
        s[t] += u;
        __syncthreads();
    }
    if (t < nblk) cnt2d[b * nblk + t] = s[t] - v;
    if (t == nblk - 1) totals[b] = s[t];
}

__global__ __launch_bounds__(128) void scanB2(const int* __restrict__ totals, int* __restrict__ bbase,
                                              int* __restrict__ row_ptr, int nbkt, int n, int e) {
    __shared__ int s[128];
    int t = threadIdx.x;
    int v = (t < nbkt) ? totals[t] : 0;
    s[t] = v;
    __syncthreads();
    for (int off = 1; off < 128; off <<= 1) {
        int u = (t >= off) ? s[t - off] : 0;
        __syncthreads();
        s[t] += u;
        __syncthreads();
    }
    if (t < nbkt) bbase[t] = s[t] - v;
    if (t == 0) row_ptr[n] = e;
}

__global__ __launch_bounds__(256) void binC(const int* __restrict__ src, const int* __restrict__ dst,
                                            const int* __restrict__ cnt2d, const int* __restrict__ bbase,
                                            unsigned* __restrict__ pairs, int e, int nbkt, int nblk) {
    __shared__ int hist[MAXBKT], loff[MAXBKT], cur[MAXBKT], gb[MAXBKT];
    __shared__ int sc[256];
    __shared__ unsigned sorted[EPB];
    int t = threadIdx.x, blk = blockIdx.x;
    for (int b = t; b < nbkt; b += 256) hist[b] = 0;
    __syncthreads();
    int base = blk * EPB;
    int cnt = min(EPB, e - base);
    unsigned packed[NE];
    int bb[NE];
#pragma unroll
    for (int j = 0; j < NE; j++) {
        int idx = base + t + 256 * j;
        bb[j] = -1;
        if (idx < e) {
            unsigned s0 = (unsigned)src[idx], d = (unsigned)dst[idx];
            int b = (int)(d >> BSH);
            bb[j] = b;
            packed[j] = s0 | ((d & ((1u << BSH) - 1)) << 16) | ((unsigned)b << 25);
            atomicAdd(&hist[b], 1);
        }
    }
    __syncthreads();
    int v = (t < nbkt) ? hist[t] : 0;
    sc[t] = v;
    __syncthreads();
    for (int off = 1; off < 256; off <<= 1) {
        int u = (t >= off) ? sc[t - off] : 0;
        __syncthreads();
        sc[t] += u;
        __syncthreads();
    }
    if (t < nbkt) {
        int ex = sc[t] - v;
        loff[t] = ex;
        cur[t] = ex;
        gb[t] = bbase[t] + cnt2d[t * nblk + blk];
    }
    __syncthreads();
#pragma unroll
    for (int j = 0; j < NE; j++) {
        if (bb[j] >= 0) {
            int r = atomicAdd(&cur[bb[j]], 1);  // LDS only
            sorted[r] = packed[j];
        }
    }
    __syncthreads();
    for (int i = t; i < cnt; i += 256) {
        unsigned w = sorted[i];
        int b = (int)(w >> 25);
        pairs[gb[b] + (i - loff[b])] = w;
    }
}

__global__ __launch_bounds__(512) void buildD(const unsigned* __restrict__ pairs,
                                              const int* __restrict__ totals, const int* __restrict__ bbase,
                                              int* __restrict__ row_ptr, unsigned short* __restrict__ csr, int n) {
    __shared__ int hist[512], off[512];
    __shared__ unsigned short lcsr[DCAP];
    int t = threadIdx.x, b = blockIdx.x;
    int cnt = totals[b], base = bbase[b];
    hist[t] = 0;
    __syncthreads();
    for (int i = t; i < cnt; i += 512)
        atomicAdd(&hist[(pairs[base + i] >> 16) & 511], 1);
    __syncthreads();
    int v = hist[t];
    off[t] = v;
    __syncthreads();
    for (int o = 1; o < 512; o <<= 1) {
        int u = (t >= o) ? off[t - o] : 0;
        __syncthreads();
        off[t] += u;
        __syncthreads();
    }
    int excl = off[t] - v;
    int node = (b << BSH) + t;
    if (node < n) row_ptr[node] = base + excl;
    __syncthreads();
    hist[t] = excl;
    __syncthreads();
    for (int i = t; i < cnt; i += 512) {
        unsigned w = pairs[base + i];
        int r = atomicAdd(&hist[(w >> 16) & 511], 1);  // LDS only
        if (r < DCAP) lcsr[r] = (unsigned short)(w & 0xFFFFu);
    }
    __syncthreads();
    int lim = min(cnt, DCAP);
    for (int i = t; i < lim; i += 512) csr[base + i] = lcsr[i];
}

// ---------------- Fused layer: degree-balanced agg -> fp32 LDS tile -> MFMA GEMM [-> GEMM2] ----------------
// Block = 256 threads, 16 nodes. Edge range [row_ptr[r0], row_ptr[r0+16]) split evenly
// across 16 slot-groups (slot = t>>4); each slot-group's 16 chunk-lanes load coalesced
// 256B rows. Segment sums flushed to fp32 tile via LDS atomicAdd at node boundaries.

template <bool SECOND>
__global__ __launch_bounds__(256) void fused_layer(
    const uint4* __restrict__ x, const int* __restrict__ row_ptr,
    const unsigned short* __restrict__ csr,
    const short8* __restrict__ Bt, const float* __restrict__ bias,
    unsigned short* __restrict__ out_h,   // !SECOND
    const short8* __restrict__ Bt2,       // SECOND
    unsigned short* __restrict__ out_y,   // SECOND
    int n) {
    __shared__ float Af[16][132];   // fp32 acc tile, +4 pad
    __shared__ int rp[17];
    __shared__ unsigned short Hs[SECOND ? 16 : 1][SECOND ? 136 : 1];

    int t = threadIdx.x;
    int r0 = blockIdx.x * 16;
    if (t < 17) rp[t] = row_ptr[min(r0 + t, n)];

    // self-feature init (plain stores)
    {
        int nl = t >> 4, chunk = t & 15;
        int node = r0 + nl;
        float acc[8] = {0.f, 0.f, 0.f, 0.f, 0.f, 0.f, 0.f, 0.f};
        if (node < n) {
            uint4 s0 = x[(size_t)node * 16 + chunk];
            ACC8(s0)
        }
#pragma unroll
        for (int j = 0; j < 8; j++) Af[nl][chunk * 8 + j] = acc[j];
    }
    __syncthreads();

    // balanced edge phase
    {
        int col = t & 15, slot = t >> 4;
        int E0 = rp[0], E1 = rp[16];
        int Eb = E1 - E0;
        int per = (Eb + 15) >> 4;
        int ed = E0 + slot * per;
        int mye = min(ed + per, E1);
        int nd = 0;
        while (ed < mye) {
            while (nd < 15 && rp[nd + 1] <= ed) nd++;
            int stop = min(mye, rp[nd + 1]);
            float acc[8] = {0.f, 0.f, 0.f, 0.f, 0.f, 0.f, 0.f, 0.f};
            int k = ed;
            for (; k + 8 <= stop; k += 8) {
                int idx[8];
#pragma unroll
                for (int j = 0; j < 8; j++) idx[j] = csr[k + j];
                uint4 v[8];
#pragma unroll
                for (int j = 0; j < 8; j++) v[j] = x[(size_t)idx[j] * 16 + col];
#pragma unroll
                for (int j = 0; j < 8; j++) { ACC8(v[j]) }
            }
            for (; k + 4 <= stop; k += 4) {
                int i0 = csr[k], i1 = csr[k + 1], i2 = csr[k + 2], i3 = csr[k + 3];
                uint4 v0 = x[(size_t)i0 * 16 + col];
                uint4 v1 = x[(size_t)i1 * 16 + col];
                uint4 v2 = x[(size_t)i2 * 16 + col];
                uint4 v3 = x[(size_t)i3 * 16 + col];
                ACC8(v0) ACC8(v1) ACC8(v2) ACC8(v3)
            }
            for (; k < stop; ++k) {
                uint4 v0 = x[(size_t)csr[k] * 16 + col];
                ACC8(v0)
            }
#pragma unroll
            for (int j = 0; j < 8; j++) atomicAdd(&Af[nd][col * 8 + j], acc[j]);
            ed = stop;
        }
    }
    __syncthreads();

    // MFMA phase: pack bf16 frags straight from fp32 tile
    int wid = t >> 6, lane = t & 63;
    int lm = lane & 15, lq = lane >> 4;

    short8 a[4];
#pragma unroll
    for (int kc = 0; kc < 4; kc++) {
        const float* p = &Af[lm][kc * 32 + lq * 8];
        short8 s;
#pragma unroll
        for (int j = 0; j < 8; j++) s[j] = (short)f2bf(p[j]);
        a[kc] = s;
    }

    f32x4 hacc[2];
#pragma unroll
    for (int nt = 0; nt < 2; nt++) hacc[nt] = (f32x4){0.f, 0.f, 0.f, 0.f};
#pragma unroll
    for (int nt = 0; nt < 2; nt++) {
        const short8* Br = Bt + (size_t)((wid * 2 + nt) * 16 + lm) * 16;
#pragma unroll
        for (int kc = 0; kc < 4; kc++)
            hacc[nt] = __builtin_amdgcn_mfma_f32_16x16x32_bf16(a[kc], Br[kc * 4 + lq], hacc[nt], 0, 0, 0);
    }

#pragma unroll
    for (int nt = 0; nt < 2; nt++) {
        int col = (wid * 2 + nt) * 16 + lm;
        float bv = bias[col];
#pragma unroll
        for (int i = 0; i < 4; i++) {
            int row = r0 + lq * 4 + i;
            float v = fmaxf(hacc[nt][i] + bv, 0.f);
            if (SECOND) {
                Hs[lq * 4 + i][col] = f2bf(v);
            } else if (row < n) {
                out_h[(size_t)row * 128 + col] = f2bf(v);
            }
        }
    }

    if (SECOND) {
        __syncthreads();
        short8 a2[4];
#pragma unroll
        for (int kc = 0; kc < 4; kc++)
            a2[kc] = *(const short8*)&Hs[lm][kc * 32 + lq * 8];
        f32x4 yacc = (f32x4){0.f, 0.f, 0.f, 0.f};
        const short8* Br2 = Bt2 + (size_t)(wid * 16 + lm) * 16;
#pragma unroll
        for (int kc = 0; kc < 4; kc++)
            yacc = __builtin_amdgcn_mfma_f32_16x16x32_bf16(a2[kc], Br2[kc * 4 + lq], yacc, 0, 0, 0);
        int col = wid * 16 + lm;
#pragma unroll
        for (int i = 0; i < 4; i++) {
            int row = r0 + lq * 4 + i;
            if (row < n) out_y[(size_t)row * 64 + col] = f2bf(yacc[i]);
        }
    }
}

// ---------------- Final aggregation (D=64, balanced) + bo + log_softmax ----------------
// Block = 256 threads, 32 nodes; slot = t>>3 (32 slots), col = t&7.

__global__ __launch_bounds__(256) void agg_lsm(
    const uint4* __restrict__ x, float* __restrict__ out,
    const int* __restrict__ row_ptr, const unsigned short* __restrict__ csr,
    const float* __restrict__ bo, int n) {
    __shared__ float Af[32][68];
    __shared__ int rp[33];

    int t = threadIdx.x;
    int r0 = blockIdx.x * 32;
    if (t < 33) rp[t] = row_ptr[min(r0 + t, n)];

    {
        int nl = t >> 3, chunk = t & 7;
        int node = r0 + nl;
        float acc[8] = {0.f, 0.f, 0.f, 0.f, 0.f, 0.f, 0.f, 0.f};
        if (node < n) {
            uint4 s0 = x[(size_t)node * 8 + chunk];
            ACC8(s0)
        }
#pragma unroll
        for (int j = 0; j < 8; j++) Af[nl][chunk * 8 + j] = acc[j];
    }
    __syncthreads();

    {
        int col = t & 7, slot = t >> 3;
        int E0 = rp[0], E1 = rp[32];
        int Eb = E1 - E0;
        int per = (Eb + 31) >> 5;
        int ed = E0 + slot * per;
        int mye = min(ed + per, E1);
        int nd = 0;
        while (ed < mye) {
            while (nd < 31 && rp[nd + 1] <= ed) nd++;
            int stop = min(mye, rp[nd + 1]);
            float acc[8] = {0.f, 0.f, 0.f, 0.f, 0.f, 0.f, 0.f, 0.f};
            int k = ed;
            for (; k + 4 <= stop; k += 4) {
                int i0 = csr[k], i1 = csr[k + 1], i2 = csr[k + 2], i3 = csr[k + 3];
                uint4 v0 = x[(size_t)i0 * 8 + col];
                uint4 v1 = x[(size_t)i1 * 8 + col];
                uint4 v2 = x[(size_t)i2 * 8 + col];
                uint4 v3 = x[(size_t)i3 * 8 + col];
                ACC8(v0) ACC8(v1) ACC8(v2) ACC8(v3)
            }
            for (; k < stop; ++k) {
                uint4 v0 = x[(size_t)csr[k] * 8 + col];
                ACC8(v0)
            }
#pragma unroll
            for (int j = 0; j < 8; j++) atomicAdd(&Af[nd][col * 8 + j], acc[j]);
            ed = stop;
        }
    }
    __syncthreads();

    int nl = t >> 3, col = t & 7;
    int node = r0 + nl;
    if (node >= n) return;
    float acc[8];
#pragma unroll
    for (int j = 0; j < 8; j++) acc[j] = Af[nl][col * 8 + j];
    const float4* bo4 = (const float4*)bo;
    float4 bA = bo4[col * 2], bB = bo4[col * 2 + 1];
    acc[0] += bA.x; acc[1] += bA.y; acc[2] += bA.z; acc[3] += bA.w;
    acc[4] += bB.x; acc[5] += bB.y; acc[6] += bB.z; acc[7] += bB.w;
    float m = acc[0];
#pragma unroll
    for (int j = 1; j < 8; j++) m = fmaxf(m, acc[j]);
#pragma unroll
    for (int off = 1; off < 8; off <<= 1) m = fmaxf(m, __shfl_xor(m, off, 64));
    float s = 0.f;
#pragma unroll
    for (int j = 0; j < 8; j++) s += __expf(acc[j] - m);
#pragma unroll
    for (int off = 1; off < 8; off <<= 1) s += __shfl_xor(s, off, 64);
    float ls = m + __logf(s);
    float4 o0 = make_float4(acc[0] - ls, acc[1] - ls, acc[2] - ls, acc[3] - ls);
    float4 o1 = make_float4(acc[4] - ls, acc[5] - ls, acc[6] - ls, acc[7] - ls);
    float4* op = (float4*)(out + (size_t)node * 64 + col * 8);
    op[0] = o0;
    op[1] = o1;
}

// ---------------- launch ----------------

extern "C" void kernel_launch(void* const* d_in, const int* in_sizes, int n_in,
                              void* d_out, int out_size, void* d_ws, size_t ws_size,
                              hipStream_t stream) {
    const float* feature = (const float*)d_in[0];
    const int*   edges   = (const int*)d_in[1];
    const float* W1 = (const float*)d_in[2];
    const float* b1 = (const float*)d_in[3];
    const float* Wh = (const float*)d_in[4];
    const float* bh = (const float*)d_in[5];
    const float* Wo = (const float*)d_in[6];
    const float* bo = (const float*)d_in[7];

    int n = in_sizes[0] / 128;  // 50000 (< 65536 for 16-bit src packing)
    int e = in_sizes[1] / 2;    // 800000
    const int* src = edges;
    const int* dst = edges + e;

    int nbkt = (n + 511) >> BSH;
    int nblk = (e + EPB - 1) / EPB;
    int nf4 = n * 32;
    int cvtb = (nf4 + 255) / 256;

    char* ws = (char*)d_ws;
    auto take = [&](size_t bytes) {
        char* p = ws;
        ws += (bytes + 255) & ~(size_t)255;
        return p;
    };
    int* cnt2d   = (int*)take((size_t)nbkt * nblk * 4);
    int* totals  = (int*)take((size_t)nbkt * 4);
    int* bbase   = (int*)take((size_t)(nbkt + 1) * 4);
    int* row_ptr = (int*)take((size_t)(n + 1) * 4);
    unsigned* pairs = (unsigned*)take((size_t)e * 4);
    unsigned short* csr = (unsigned short*)take((size_t)e * 2);
    unsigned short* featb = (unsigned short*)take((size_t)n * 128 * 2);
    unsigned short* hb    = (unsigned short*)take((size_t)n * 128 * 2);
    unsigned short* yb    = (unsigned short*)take((size_t)n * 64 * 2);
    unsigned short* W1t = (unsigned short*)take(128 * 128 * 2);
    unsigned short* Wht = (unsigned short*)take(128 * 128 * 2);
    unsigned short* Wot = (unsigned short*)take(64 * 128 * 2);

    // CSR build + conversions (binA co-scheduled with cvt/wt)
    mega1<<<nblk + cvtb + 160, 256, 0, stream>>>(
        dst, cnt2d, e, nbkt, nblk,
        (const float4*)feature, (uint2*)featb, cvtb, nf4,
        W1, Wh, Wo, W1t, Wht, Wot);
    scanB1<<<nbkt, 512, 0, stream>>>(cnt2d, totals, nblk);
    scanB2<<<1, 128, 0, stream>>>(totals, bbase, row_ptr, nbkt, n, e);
    binC<<<nblk, 256, 0, stream>>>(src, dst, cnt2d, bbase, pairs, e, nbkt, nblk);
    buildD<<<nbkt, 512, 0, stream>>>(pairs, totals, bbase, row_ptr, csr, n);

    int fblocks = (n + 15) / 16;

    // Layer 1: h1 = relu((x+agg(x))@W1+b1)
    fused_layer<false><<<fblocks, 256, 0, stream>>>(
        (const uint4*)featb, row_ptr, csr, (const short8*)W1t, b1,
        hb, nullptr, nullptr, n);

    // Layer 2 + layer-3 GEMM: h2 = relu((h1+agg(h1))@Wh+bh); y = h2@Wo
    fused_layer<true><<<fblocks, 256, 0, stream>>>(
        (const uint4*)hb, row_ptr, csr, (const short8*)Wht, bh,
        nullptr, (const short8*)Wot, yb, n);

    // out = log_softmax(y + agg(y) + bo)
    agg_lsm<<<(n + 31) / 32, 256, 0, stream>>>(
        (const uint4*)yb, (float*)d_out, row_ptr, csr, bo, n);
}

// Round 6
// 208.944 us; speedup vs baseline: 1.6135x; 1.6135x over previous
//
#include <hip/hip_runtime.h>

typedef short short8 __attribute__((ext_vector_type(8)));
typedef float f32x4 __attribute__((ext_vector_type(4)));

// ---------------- bf16 helpers ----------------

__device__ inline unsigned short f2bf(float f) {
    union { float f; unsigned u; } v; v.f = f;
    unsigned r = v.u + 0x7fffu + ((v.u >> 16) & 1u);
    return (unsigned short)(r >> 16);
}
__device__ inline unsigned pack2(float a, float b) {
    return (unsigned)f2bf(a) | ((unsigned)f2bf(b) << 16);
}
__device__ inline float bflo(unsigned u) { union { unsigned q; float f; } c; c.q = u << 16; return c.f; }
__device__ inline float bfhi(unsigned u) { union { unsigned q; float f; } c; c.q = u & 0xffff0000u; return c.f; }

#define ACC8(vv)                                     \
    acc[0] += bflo(vv.x); acc[1] += bfhi(vv.x);      \
    acc[2] += bflo(vv.y); acc[3] += bfhi(vv.y);      \
    acc[4] += bflo(vv.z); acc[5] += bfhi(vv.z);      \
    acc[6] += bflo(vv.w); acc[7] += bfhi(vv.w);

// Gather-accumulate over edges [beg,end); geti(k) supplies the row index
// (LDS-staged on the fast path). 8-wide unroll keeps 8 row loads in flight.
template <int TPN, typename F>
__device__ __forceinline__ void gather_acc(float acc[8], const uint4* __restrict__ x,
                                           int lane, int beg, int end, F geti) {
    int k = beg;
    for (; k + 8 <= end; k += 8) {
        int idx[8];
#pragma unroll
        for (int j = 0; j < 8; j++) idx[j] = geti(k + j);
        uint4 v[8];
#pragma unroll
        for (int j = 0; j < 8; j++) v[j] = x[(size_t)idx[j] * TPN + lane];
#pragma unroll
        for (int j = 0; j < 8; j++) { ACC8(v[j]) }
    }
    for (; k + 4 <= end; k += 4) {
        int i0 = geti(k), i1 = geti(k + 1), i2 = geti(k + 2), i3 = geti(k + 3);
        uint4 v0 = x[(size_t)i0 * TPN + lane];
        uint4 v1 = x[(size_t)i1 * TPN + lane];
        uint4 v2 = x[(size_t)i2 * TPN + lane];
        uint4 v3 = x[(size_t)i3 * TPN + lane];
        ACC8(v0) ACC8(v1) ACC8(v2) ACC8(v3)
    }
    for (; k < end; ++k) {
        uint4 v0 = x[(size_t)geti(k) * TPN + lane];
        ACC8(v0)
    }
}

// ---------------- CSR build: atomic-free two-level bucket sort ----------------

#define EPB 2048
#define NE 8
#define BSH 9
#define MAXBKT 128
#define DCAP 10240

// mega1: binA (blocks [0,nblk)) + feature->bf16 cvt + weight transposes, one launch
__global__ __launch_bounds__(256) void mega1(const int* __restrict__ dst, int* __restrict__ cnt2d,
                                             int e, int nbkt, int nblk,
                                             const float4* __restrict__ feat, uint2* __restrict__ featb,
                                             int cvtb, int nf4,
                                             const float* __restrict__ W1, const float* __restrict__ Wh,
                                             const float* __restrict__ Wo,
                                             unsigned short* __restrict__ W1t, unsigned short* __restrict__ Wht,
                                             unsigned short* __restrict__ Wot) {
    __shared__ int hist[MAXBKT];
    int t = threadIdx.x, b = blockIdx.x;
    if (b < nblk) {
        for (int j = t; j < nbkt; j += 256) hist[j] = 0;
        __syncthreads();
        int base = b * EPB;
#pragma unroll
        for (int j = 0; j < NE; j++) {
            int idx = base + t + 256 * j;
            if (idx < e) atomicAdd(&hist[dst[idx] >> BSH], 1);
        }
        __syncthreads();
        for (int j = t; j < nbkt; j += 256) cnt2d[j * nblk + b] = hist[j];
    } else if (b < nblk + cvtb) {
        int i = (b - nblk) * 256 + t;
        if (i < nf4) {
            float4 v = feat[i];
            featb[i] = make_uint2(pack2(v.x, v.y), pack2(v.z, v.w));
        }
    } else {
        int i = (b - nblk - cvtb) * 256 + t;
        if (i < 16384) {
            int k = i >> 7, nn = i & 127;
            W1t[nn * 128 + k] = f2bf(W1[i]);
        } else if (i < 32768) {
            int j = i - 16384, k = j >> 7, nn = j & 127;
            Wht[nn * 128 + k] = f2bf(Wh[j]);
        } else if (i < 40960) {
            int j = i - 32768, k = j >> 6, nn = j & 63;
            Wot[nn * 128 + k] = f2bf(Wo[j]);
        }
    }
}

__global__ __launch_bounds__(512) void scanB1(int* __restrict__ cnt2d, int* __restrict__ totals, int nblk) {
    __shared__ int s[512];
    int t = threadIdx.x, b = blockIdx.x;
    int v = (t < nblk) ? cnt2d[b * nblk + t] : 0;
    s[t] = v;
    __syncthreads();
    for (int off = 1; off < 512; off <<= 1) {
        int u = (t >= off) ? s[t - off] : 0;
        __syncthreads();
        s[t] += u;
        __syncthreads();
    }
    if (t < nblk) cnt2d[b * nblk + t] = s[t] - v;
    if (t == nblk - 1) totals[b] = s[t];
}

__global__ __launch_bounds__(128) void scanB2(const int* __restrict__ totals, int* __restrict__ bbase,
                                              int* __restrict__ row_ptr, int nbkt, int n, int e) {
    __shared__ int s[128];
    int t = threadIdx.x;
    int v = (t < nbkt) ? totals[t] : 0;
    s[t] = v;
    __syncthreads();
    for (int off = 1; off < 128; off <<= 1) {
        int u = (t >= off) ? s[t - off] : 0;
        __syncthreads();
        s[t] += u;
        __syncthreads();
    }
    if (t < nbkt) bbase[t] = s[t] - v;
    if (t == 0) row_ptr[n] = e;
}

__global__ __launch_bounds__(256) void binC(const int* __restrict__ src, const int* __restrict__ dst,
                                            const int* __restrict__ cnt2d, const int* __restrict__ bbase,
                                            unsigned* __restrict__ pairs, int e, int nbkt, int nblk) {
    __shared__ int hist[MAXBKT], loff[MAXBKT], cur[MAXBKT], gb[MAXBKT];
    __shared__ int sc[256];
    __shared__ unsigned sorted[EPB];
    int t = threadIdx.x, blk = blockIdx.x;
    for (int b = t; b < nbkt; b += 256) hist[b] = 0;
    __syncthreads();
    int base = blk * EPB;
    int cnt = min(EPB, e - base);
    unsigned packed[NE];
    int bb[NE];
#pragma unroll
    for (int j = 0; j < NE; j++) {
        int idx = base + t + 256 * j;
        bb[j] = -1;
        if (idx < e) {
            unsigned s0 = (unsigned)src[idx], d = (unsigned)dst[idx];
            int b = (int)(d >> BSH);
            bb[j] = b;
            packed[j] = s0 | ((d & ((1u << BSH) - 1)) << 16) | ((unsigned)b << 25);
            atomicAdd(&hist[b], 1);
        }
    }
    __syncthreads();
    int v = (t < nbkt) ? hist[t] : 0;
    sc[t] = v;
    __syncthreads();
    for (int off = 1; off < 256; off <<= 1) {
        int u = (t >= off) ? sc[t - off] : 0;
        __syncthreads();
        sc[t] += u;
        __syncthreads();
    }
    if (t < nbkt) {
        int ex = sc[t] - v;
        loff[t] = ex;
        cur[t] = ex;
        gb[t] = bbase[t] + cnt2d[t * nblk + blk];
    }
    __syncthreads();
#pragma unroll
    for (int j = 0; j < NE; j++) {
        if (bb[j] >= 0) {
            int r = atomicAdd(&cur[bb[j]], 1);  // LDS only
            sorted[r] = packed[j];
        }
    }
    __syncthreads();
    for (int i = t; i < cnt; i += 256) {
        unsigned w = sorted[i];
        int b = (int)(w >> 25);
        pairs[gb[b] + (i - loff[b])] = w;
    }
}

__global__ __launch_bounds__(512) void buildD(const unsigned* __restrict__ pairs,
                                              const int* __restrict__ totals, const int* __restrict__ bbase,
                                              int* __restrict__ row_ptr, unsigned short* __restrict__ csr, int n) {
    __shared__ int hist[512], off[512];
    __shared__ unsigned short lcsr[DCAP];
    int t = threadIdx.x, b = blockIdx.x;
    int cnt = totals[b], base = bbase[b];
    hist[t] = 0;
    __syncthreads();
    for (int i = t; i < cnt; i += 512)
        atomicAdd(&hist[(pairs[base + i] >> 16) & 511], 1);
    __syncthreads();
    int v = hist[t];
    off[t] = v;
    __syncthreads();
    for (int o = 1; o < 512; o <<= 1) {
        int u = (t >= o) ? off[t - o] : 0;
        __syncthreads();
        off[t] += u;
        __syncthreads();
    }
    int excl = off[t] - v;
    int node = (b << BSH) + t;
    if (node < n) row_ptr[node] = base + excl;
    __syncthreads();
    hist[t] = excl;
    __syncthreads();
    for (int i = t; i < cnt; i += 512) {
        unsigned w = pairs[base + i];
        int r = atomicAdd(&hist[(w >> 16) & 511], 1);  // LDS only
        if (r < DCAP) lcsr[r] = (unsigned short)(w & 0xFFFFu);
    }
    __syncthreads();
    int lim = min(cnt, DCAP);
    for (int i = t; i < lim; i += 512) csr[base + i] = lcsr[i];
}

// ---------------- Fused layer (R4 structure + LDS-staged edge indices) ----------------
// Block = 256 threads = 16 nodes x 16 chunks. Tile rows exactly match one MFMA 16-row strip.

#define ECAP 1024   // block edge-index LDS cap; mean 256, >40 sigma headroom

template <bool SECOND>
__global__ __launch_bounds__(256) void fused_layer(
    const uint4* __restrict__ x, const int* __restrict__ row_ptr,
    const unsigned short* __restrict__ csr,
    const short8* __restrict__ Bt, const float* __restrict__ bias,
    unsigned short* __restrict__ out_h,   // !SECOND
    const short8* __restrict__ Bt2,       // SECOND
    unsigned short* __restrict__ out_y,   // SECOND
    int n) {
    __shared__ unsigned short As[16][136];  // +8 halves pad
    __shared__ unsigned short Hs[SECOND ? 16 : 1][SECOND ? 136 : 1];
    __shared__ unsigned short eidx[ECAP];

    int t = threadIdx.x;
    int nl = t >> 4, chunk = t & 15;
    int r0 = blockIdx.x * 16;
    int node = r0 + nl;

    // stage this block's (contiguous) edge indices into LDS
    int E0 = row_ptr[r0 < n ? r0 : n];
    int E1 = row_ptr[min(r0 + 16, n)];
    int ecnt = min(E1 - E0, ECAP);
    for (int i = t; i < ecnt; i += 256) eidx[i] = csr[E0 + i];
    __syncthreads();

    // ---- Phase 1: aggregation into registers ----
    float acc[8] = {0.f, 0.f, 0.f, 0.f, 0.f, 0.f, 0.f, 0.f};
    if (node < n) {
        uint4 s0 = x[(size_t)node * 16 + chunk];
        ACC8(s0)
        int beg = row_ptr[node], end = row_ptr[node + 1];
        if (end - E0 <= ECAP) {
            gather_acc<16>(acc, x, chunk, beg - E0, end - E0,
                           [&](int k) { return (int)eidx[k]; });
        } else {
            gather_acc<16>(acc, x, chunk, beg, end,
                           [&](int k) { return (int)csr[k]; });
        }
    }
    uint4 packed;
    packed.x = pack2(acc[0], acc[1]); packed.y = pack2(acc[2], acc[3]);
    packed.z = pack2(acc[4], acc[5]); packed.w = pack2(acc[6], acc[7]);
    ((uint4*)&As[nl][0])[chunk] = packed;
    __syncthreads();

    // ---- Phase 2: GEMM 16x128 @ 128x128 ----
    int wid = t >> 6, lane = t & 63;
    int lm = lane & 15, lq = lane >> 4;

    short8 a[4];
#pragma unroll
    for (int kc = 0; kc < 4; kc++)
        a[kc] = *(const short8*)&As[lm][kc * 32 + lq * 8];

    f32x4 hacc[2];
#pragma unroll
    for (int nt = 0; nt < 2; nt++) hacc[nt] = (f32x4){0.f, 0.f, 0.f, 0.f};
#pragma unroll
    for (int nt = 0; nt < 2; nt++) {
        const short8* Br = Bt + (size_t)((wid * 2 + nt) * 16 + lm) * 16;
#pragma unroll
        for (int kc = 0; kc < 4; kc++)
            hacc[nt] = __builtin_amdgcn_mfma_f32_16x16x32_bf16(a[kc], Br[kc * 4 + lq], hacc[nt], 0, 0, 0);
    }

    // ---- Epilogue ----
#pragma unroll
    for (int nt = 0; nt < 2; nt++) {
        int col = (wid * 2 + nt) * 16 + lm;
        float bv = bias[col];
#pragma unroll
        for (int i = 0; i < 4; i++) {
            int row = r0 + lq * 4 + i;
            float v = fmaxf(hacc[nt][i] + bv, 0.f);
            if (SECOND) {
                Hs[lq * 4 + i][col] = f2bf(v);
            } else if (row < n) {
                out_h[(size_t)row * 128 + col] = f2bf(v);
            }
        }
    }

    if (SECOND) {
        __syncthreads();
        short8 a2[4];
#pragma unroll
        for (int kc = 0; kc < 4; kc++)
            a2[kc] = *(const short8*)&Hs[lm][kc * 32 + lq * 8];
        f32x4 yacc = (f32x4){0.f, 0.f, 0.f, 0.f};
        const short8* Br2 = Bt2 + (size_t)(wid * 16 + lm) * 16;
#pragma unroll
        for (int kc = 0; kc < 4; kc++)
            yacc = __builtin_amdgcn_mfma_f32_16x16x32_bf16(a2[kc], Br2[kc * 4 + lq], yacc, 0, 0, 0);
        int col = wid * 16 + lm;
#pragma unroll
        for (int i = 0; i < 4; i++) {
            int row = r0 + lq * 4 + i;
            if (row < n) out_y[(size_t)row * 64 + col] = f2bf(yacc[i]);
        }
    }
}

// ---------------- Final aggregation (D=64) + bo + log_softmax (R4 + LDS indices) ----------------
// Block = 256 threads = 32 nodes x 8 chunks.

#define ECAP2 1536  // mean 512, >40 sigma headroom

__global__ __launch_bounds__(256) void agg_lsm(
    const uint4* __restrict__ x, float* __restrict__ out,
    const int* __restrict__ row_ptr, const unsigned short* __restrict__ csr,
    const float* __restrict__ bo, int n) {
    __shared__ unsigned short eidx[ECAP2];
    int t = threadIdx.x;
    int r0 = blockIdx.x * 32;
    int node = r0 + (t >> 3), lane = t & 7;

    int E0 = row_ptr[r0 < n ? r0 : n];
    int E1 = row_ptr[min(r0 + 32, n)];
    int ecnt = min(E1 - E0, ECAP2);
    for (int i = t; i < ecnt; i += 256) eidx[i] = csr[E0 + i];
    __syncthreads();

    if (node >= n) return;
    uint4 s0 = x[(size_t)node * 8 + lane];
    float acc[8] = { bflo(s0.x), bfhi(s0.x), bflo(s0.y), bfhi(s0.y),
                     bflo(s0.z), bfhi(s0.z), bflo(s0.w), bfhi(s0.w) };
    int beg = row_ptr[node], end = row_ptr[node + 1];
    if (end - E0 <= ECAP2) {
        gather_acc<8>(acc, x, lane, beg - E0, end - E0,
                      [&](int k) { return (int)eidx[k]; });
    } else {
        gather_acc<8>(acc, x, lane, beg, end,
                      [&](int k) { return (int)csr[k]; });
    }

    const float4* bo4 = (const float4*)bo;
    float4 bA = bo4[lane * 2], bB = bo4[lane * 2 + 1];
    acc[0] += bA.x; acc[1] += bA.y; acc[2] += bA.z; acc[3] += bA.w;
    acc[4] += bB.x; acc[5] += bB.y; acc[6] += bB.z; acc[7] += bB.w;
    float m = acc[0];
#pragma unroll
    for (int j = 1; j < 8; j++) m = fmaxf(m, acc[j]);
#pragma unroll
    for (int off = 1; off < 8; off <<= 1) m = fmaxf(m, __shfl_xor(m, off, 64));
    float s = 0.f;
#pragma unroll
    for (int j = 0; j < 8; j++) s += __expf(acc[j] - m);
#pragma unroll
    for (int off = 1; off < 8; off <<= 1) s += __shfl_xor(s, off, 64);
    float ls = m + __logf(s);
    float4 o0 = make_float4(acc[0] - ls, acc[1] - ls, acc[2] - ls, acc[3] - ls);
    float4 o1 = make_float4(acc[4] - ls, acc[5] - ls, acc[6] - ls, acc[7] - ls);
    float4* op = (float4*)(out + (size_t)node * 64 + lane * 8);
    op[0] = o0;
    op[1] = o1;
}

// ---------------- launch ----------------

extern "C" void kernel_launch(void* const* d_in, const int* in_sizes, int n_in,
                              void* d_out, int out_size, void* d_ws, size_t ws_size,
                              hipStream_t stream) {
    const float* feature = (const float*)d_in[0];
    const int*   edges   = (const int*)d_in[1];
    const float* W1 = (const float*)d_in[2];
    const float* b1 = (const float*)d_in[3];
    const float* Wh = (const float*)d_in[4];
    const float* bh = (const float*)d_in[5];
    const float* Wo = (const float*)d_in[6];
    const float* bo = (const float*)d_in[7];

    int n = in_sizes[0] / 128;  // 50000 (< 65536 for 16-bit src packing)
    int e = in_sizes[1] / 2;    // 800000
    const int* src = edges;
    const int* dst = edges + e;

    int nbkt = (n + 511) >> BSH;
    int nblk = (e + EPB - 1) / EPB;
    int nf4 = n * 32;
    int cvtb = (nf4 + 255) / 256;

    char* ws = (char*)d_ws;
    auto take = [&](size_t bytes) {
        char* p = ws;
        ws += (bytes + 255) & ~(size_t)255;
        return p;
    };
    int* cnt2d   = (int*)take((size_t)nbkt * nblk * 4);
    int* totals  = (int*)take((size_t)nbkt * 4);
    int* bbase   = (int*)take((size_t)(nbkt + 1) * 4);
    int* row_ptr = (int*)take((size_t)(n + 1) * 4);
    unsigned* pairs = (unsigned*)take((size_t)e * 4);
    unsigned short* csr = (unsigned short*)take((size_t)e * 2);
    unsigned short* featb = (unsigned short*)take((size_t)n * 128 * 2);
    unsigned short* hb    = (unsigned short*)take((size_t)n * 128 * 2);
    unsigned short* yb    = (unsigned short*)take((size_t)n * 64 * 2);
    unsigned short* W1t = (unsigned short*)take(128 * 128 * 2);
    unsigned short* Wht = (unsigned short*)take(128 * 128 * 2);
    unsigned short* Wot = (unsigned short*)take(64 * 128 * 2);

    // CSR build + conversions (binA co-scheduled with cvt/wt)
    mega1<<<nblk + cvtb + 160, 256, 0, stream>>>(
        dst, cnt2d, e, nbkt, nblk,
        (const float4*)feature, (uint2*)featb, cvtb, nf4,
        W1, Wh, Wo, W1t, Wht, Wot);
    scanB1<<<nbkt, 512, 0, stream>>>(cnt2d, totals, nblk);
    scanB2<<<1, 128, 0, stream>>>(totals, bbase, row_ptr, nbkt, n, e);
    binC<<<nblk, 256, 0, stream>>>(src, dst, cnt2d, bbase, pairs, e, nbkt, nblk);
    buildD<<<nbkt, 512, 0, stream>>>(pairs, totals, bbase, row_ptr, csr, n);

    int fblocks = (n + 15) / 16;

    // Layer 1: h1 = relu((x+agg(x))@W1+b1)
    fused_layer<false><<<fblocks, 256, 0, stream>>>(
        (const uint4*)featb, row_ptr, csr, (const short8*)W1t, b1,
        hb, nullptr, nullptr, n);

    // Layer 2 + layer-3 GEMM: h2 = relu((h1+agg(h1))@Wh+bh); y = h2@Wo
    fused_layer<true><<<fblocks, 256, 0, stream>>>(
        (const uint4*)hb, row_ptr, csr, (const short8*)Wht, bh,
        nullptr, (const short8*)Wot, yb, n);

    // out = log_softmax(y + agg(y) + bo)
    agg_lsm<<<(n + 31) / 32, 256, 0, stream>>>(
        (const uint4*)yb, (float*)d_out, row_ptr, csr, bo, n);
}